// Round 19
// baseline (187.103 us; speedup 1.0000x reference)
//
#include <hip/hip_runtime.h>
#include <hip/hip_bf16.h>
#include <math.h>

#define N 320
#define C 128
#define A 32
#define H 4
#define NPOS (N*N)

typedef __attribute__((ext_vector_type(8))) __bf16 bf16x8;
typedef __attribute__((ext_vector_type(16))) float f32x16;

union frag_u { int4 i; bf16x8 v; unsigned u[4]; };

#define MFMA32(va, vb, vc) __builtin_amdgcn_mfma_f32_32x32x16_bf16((va), (vb), (vc), 0, 0, 0)

extern "C" __device__ float __ocml_native_exp2_f32(float);

// wave-local LDS fence: order ds_write -> ds_read within a wave without
// draining vmcnt (global stores stay in flight).
#define WAVE_LDS_FENCE() do { \
    asm volatile("s_waitcnt lgkmcnt(0)" ::: "memory"); \
    __builtin_amdgcn_sched_barrier(0); \
} while (0)

static __device__ __forceinline__ unsigned pk_bf16(float lo, float hi) {
    union { __hip_bfloat162 h; unsigned u; } cv;
    cv.h = __float22bfloat162_rn(make_float2(lo, hi));
    return cv.u;
}

static __device__ __forceinline__ float bf16_to_f32(unsigned short u) {
    union { unsigned u; float f; } c;
    c.u = ((unsigned)u) << 16;
    return c.f;
}

// ---------------- Kernel W: weights -> bf16 B-fragment order ----------------
__global__ __launch_bounds__(256)
void wprep_kernel(const float* __restrict__ Wq,
                  const float* __restrict__ Wk,
                  const float* __restrict__ Wv,
                  const float* __restrict__ Wg,
                  const float* __restrict__ Wo,
                  unsigned short* __restrict__ WF) {
    const float isq = 0.17677669529663687f; // 1/sqrt(32)
    int tid = blockIdx.x * 256 + threadIdx.x;   // 10240 total
    int lane = tid & 63;
    int kk = (tid >> 6) & 7;
    int ct = (tid >> 9) & 3;
    int mat = tid >> 11;                        // 0..4
    const float* src = (mat == 0) ? Wq : (mat == 1) ? Wk : (mat == 2) ? Wv
                     : (mat == 3) ? Wg : Wo;
    float scl = (mat == 0) ? isq : 1.0f;
    int col = ct * 32 + (lane & 31);
    int c0 = kk * 16 + (lane >> 5) * 8;
    float v[8];
    #pragma unroll
    for (int e = 0; e < 8; e++) {
        int rr = c0 + e;
        int srow = (mat == 4) ? (((rr & 31) << 2) | (rr >> 5)) : rr;
        v[e] = src[(size_t)srow * 128 + col] * scl;
    }
    int4 out;
    out.x = pk_bf16(v[0], v[1]);
    out.y = pk_bf16(v[2], v[3]);
    out.z = pk_bf16(v[4], v[5]);
    out.w = pk_bf16(v[6], v[7]);
    *(int4*)((char*)WF + (size_t)tid * 16) = out;
}

// ---------------- Kernel T: bias transpose Bp[h][k*N+j] -> BpT[h][j*N+k] ----------------
__global__ __launch_bounds__(256)
void btrans_kernel(const float* __restrict__ Bp, float* __restrict__ BpT) {
    __shared__ float tile[64][65];
    const int b = blockIdx.x;
    const int h = b / 25;
    const int bk = (b % 25) / 5;
    const int bj = b % 5;
    const int k0 = bk * 64, j0 = bj * 64;
    const float* src = Bp + (size_t)h * NPOS;
    float* dst = BpT + (size_t)h * NPOS;
    const int t = threadIdx.x;
    #pragma unroll
    for (int u = 0; u < 16; ++u) {
        int idx = u * 256 + t;
        int kk = idx >> 6, jj = idx & 63;
        tile[kk][jj] = src[(size_t)(k0 + kk) * N + j0 + jj];
    }
    __syncthreads();
    #pragma unroll
    for (int u = 0; u < 16; ++u) {
        int idx = u * 256 + t;
        int jj = idx >> 6, kk = idx & 63;
        dst[(size_t)(j0 + jj) * N + k0 + kk] = tile[kk][jj];
    }
}

// ---------------- Kernel A: LayerNorm + MFMA projections ----------------
// 3200 blocks x 256 threads; 32 positions per block; wave w computes matrix w.
// V wave stores DIRECT from accumulator (lane=channel, regs=positions) --
// skips its LDS stage round-trip and both fences.
__global__ __launch_bounds__(256)
void ln_proj_kernel(const float* __restrict__ x2d,
                    const float* __restrict__ norm_w,
                    const float* __restrict__ norm_b,
                    const float* __restrict__ Wb,
                    const float* __restrict__ bg,
                    const unsigned short* __restrict__ WF,
                    unsigned short* __restrict__ Qb,
                    unsigned short* __restrict__ Kb,
                    unsigned short* __restrict__ Vta,
                    unsigned short* __restrict__ Gb,
                    float* __restrict__ Bp) {
    // overlay: xnb (8192 B, dead after A-frag load) aliases stage (16896 B)
    __shared__ __align__(16) unsigned char shbuf[16896];
    unsigned char* xnb = shbuf;                 // bf16 [32][128], swizzled granules

    const int t = threadIdx.x;
    const int gpos0 = blockIdx.x * 32;

    // ---- Phase 1: LN + bias projection + bf16 pack to LDS ----
    {
        const int r = t >> 3, s = t & 7;
        const float4* src = (const float4*)(x2d + (size_t)(gpos0 + r) * 128 + s * 16);
        float4 xv[4];
        #pragma unroll
        for (int u = 0; u < 4; u++) xv[u] = src[u];
        float sum = 0.f, sq = 0.f;
        #pragma unroll
        for (int u = 0; u < 4; u++) {
            sum += xv[u].x + xv[u].y + xv[u].z + xv[u].w;
            sq += xv[u].x * xv[u].x + xv[u].y * xv[u].y
                + xv[u].z * xv[u].z + xv[u].w * xv[u].w;
        }
        sum += __shfl_xor(sum, 1); sum += __shfl_xor(sum, 2); sum += __shfl_xor(sum, 4);
        sq  += __shfl_xor(sq, 1);  sq  += __shfl_xor(sq, 2);  sq  += __shfl_xor(sq, 4);
        float mean = sum * (1.0f / 128.0f);
        float var  = sq * (1.0f / 128.0f) - mean * mean;
        float rstd = rsqrtf(var + 1e-5f);

        const float4* wsrc = (const float4*)(norm_w + s * 16);
        const float4* bsrc = (const float4*)(norm_b + s * 16);
        const float4* wb4  = (const float4*)Wb;
        float pb0 = 0.f, pb1 = 0.f, pb2 = 0.f, pb3 = 0.f;
        float4 xe;
        #pragma unroll
        for (int u = 0; u < 4; u++) {
            float4 wv = wsrc[u], bv = bsrc[u], x4 = xv[u];
            float4 xn;
            xn.x = (x4.x - mean) * rstd * wv.x + bv.x;
            xn.y = (x4.y - mean) * rstd * wv.y + bv.y;
            xn.z = (x4.z - mean) * rstd * wv.z + bv.z;
            xn.w = (x4.w - mean) * rstd * wv.w + bv.w;
            int cb = s * 16 + u * 4;
            float4 w0 = wb4[cb + 0], w1 = wb4[cb + 1], w2 = wb4[cb + 2], w3 = wb4[cb + 3];
            pb0 = fmaf(xn.x, w0.x, fmaf(xn.y, w1.x, fmaf(xn.z, w2.x, fmaf(xn.w, w3.x, pb0))));
            pb1 = fmaf(xn.x, w0.y, fmaf(xn.y, w1.y, fmaf(xn.z, w2.y, fmaf(xn.w, w3.y, pb1))));
            pb2 = fmaf(xn.x, w0.z, fmaf(xn.y, w1.z, fmaf(xn.z, w2.z, fmaf(xn.w, w3.z, pb2))));
            pb3 = fmaf(xn.x, w0.w, fmaf(xn.y, w1.w, fmaf(xn.z, w2.w, fmaf(xn.w, w3.w, pb3))));
            if (u & 1) {
                int g = s * 2 + (u >> 1);
                int4 gr;
                gr.x = pk_bf16(xe.x, xe.y);
                gr.y = pk_bf16(xe.z, xe.w);
                gr.z = pk_bf16(xn.x, xn.y);
                gr.w = pk_bf16(xn.z, xn.w);
                *(int4*)(xnb + r * 256 + ((g ^ (r & 7)) << 4)) = gr;
            } else {
                xe = xn;
            }
        }
        pb0 += __shfl_xor(pb0, 1); pb0 += __shfl_xor(pb0, 2); pb0 += __shfl_xor(pb0, 4);
        pb1 += __shfl_xor(pb1, 1); pb1 += __shfl_xor(pb1, 2); pb1 += __shfl_xor(pb1, 4);
        pb2 += __shfl_xor(pb2, 1); pb2 += __shfl_xor(pb2, 2); pb2 += __shfl_xor(pb2, 4);
        pb3 += __shfl_xor(pb3, 1); pb3 += __shfl_xor(pb3, 2); pb3 += __shfl_xor(pb3, 4);
        if (s < 4) {
            float pbsel = (s == 0) ? pb0 : (s == 1) ? pb1 : (s == 2) ? pb2 : pb3;
            Bp[(size_t)s * NPOS + gpos0 + r] = pbsel;
        }
    }
    __syncthreads();

    // ---- Phase 2: per-wave MFMA GEMM + epilogue ----
    const int lane = t & 63;
    const int w = t >> 6;
    const int col = lane & 31;
    const int hi = lane >> 5;

    frag_u af[8];
    #pragma unroll
    for (int kk = 0; kk < 8; kk++)
        af[kk].i = *(const int4*)(xnb + col * 256 + (((kk * 2 + hi) ^ (col & 7)) << 4));
    __syncthreads();   // xnb dead; stage may now alias it

    const char* wf = (const char*)WF + (size_t)w * 4 * 8 * 1024;
    float* stage_w = (float*)shbuf + w * 1056;   // 32*33 floats per wave

    for (int ct = 0; ct < 4; ct++) {
        f32x16 acc;
        #pragma unroll
        for (int r = 0; r < 16; r++) acc[r] = 0.f;
        #pragma unroll
        for (int kk = 0; kk < 8; kk++) {
            frag_u bf;
            bf.i = *(const int4*)(wf + (ct * 8 + kk) * 1024 + lane * 16);
            acc = MFMA32(af[kk].v, bf.v, acc);
        }

        if (w == 2) {
            // V planes [h*32+a][pos]: direct store from acc.
            // lane col = out-channel; reg r -> pos = (r&3) + 8*(r>>2) + 4*hi.
            int plane = (col & 3) * 32 + ct * 8 + (col >> 2);
            char* pb = (char*)Vta + ((size_t)plane * NPOS + gpos0 + 4 * hi) * 2;
            #pragma unroll
            for (int m = 0; m < 4; ++m) {
                uint2 val;
                val.x = pk_bf16(acc[4 * m + 0], acc[4 * m + 1]);
                val.y = pk_bf16(acc[4 * m + 2], acc[4 * m + 3]);
                *(uint2*)(pb + (8 * m) * 2) = val;
            }
            continue;
        }

        // stage: [out-ch col][pos patr], stride 33
        #pragma unroll
        for (int r = 0; r < 16; r++) {
            int patr = (r & 3) + 8 * (r >> 2) + 4 * hi;
            stage_w[col * 33 + patr] = acc[r];
        }
        WAVE_LDS_FENCE();   // lgkmcnt only: stage visible wave-wide, stores stay in flight
        if (w < 2) {
            // Q / K granule planes [h*4+ct][pos][16B]; hi-half writes 8B
            char* dst = (w == 0) ? (char*)Qb : (char*)Kb;
            #pragma unroll
            for (int h = 0; h < 4; h++) {
                float f[4];
                #pragma unroll
                for (int e = 0; e < 4; e++)
                    f[e] = stage_w[((hi * 4 + e) * 4 + h) * 33 + col];
                uint2 val;
                val.x = pk_bf16(f[0], f[1]);
                val.y = pk_bf16(f[2], f[3]);
                *(uint2*)(dst + ((size_t)(h * 4 + ct) * NPOS + gpos0 + col) * 16 + hi * 8) = val;
            }
        } else {
            // G granule planes [h*4+ct][pos][16B], sigmoid(acc + bg); hi-half 8B
            #pragma unroll
            for (int h = 0; h < 4; h++) {
                float f[4];
                #pragma unroll
                for (int e = 0; e < 4; e++) {
                    float z = stage_w[((hi * 4 + e) * 4 + h) * 33 + col]
                            + bg[ct * 32 + (hi * 4 + e) * 4 + h];
                    f[e] = 1.0f / (1.0f + __expf(-z));
                }
                uint2 val;
                val.x = pk_bf16(f[0], f[1]);
                val.y = pk_bf16(f[2], f[3]);
                *(uint2*)((char*)Gb + ((size_t)(h * 4 + ct) * NPOS + gpos0 + col) * 16 + hi * 8) = val;
            }
        }
        WAVE_LDS_FENCE();   // reads done before next ct overwrites stage
    }
}

// ---------------- Kernel B: MFMA attention per (i,h) ----------------
// round-15 structure; exp computed as exp2 with log2e folded into the mask
// arrays (deletes 32 v_mul per kt from the sv->exp critical chain).
__global__ __launch_bounds__(320, 2)
void attn_kernel(const unsigned short* __restrict__ Qb,
                 const unsigned short* __restrict__ Kb,
                 const unsigned short* __restrict__ Vta,
                 const unsigned short* __restrict__ Gb,
                 const float* __restrict__ BpT,
                 const float* __restrict__ mask,
                 unsigned short* __restrict__ Ob) {
    __shared__ __align__(16) unsigned char smem[40960];   // K[20480] | V[20480]; reused as epilogue stage
    __shared__ float mparr[320];   // mask*log2e, MFMA-row order
    __shared__ float m2arr[320];   // (100*mask-100)*log2e, MFMA-row order
    unsigned char* Klds = smem;
    unsigned char* Vlds = smem + 20480;

    const int i = blockIdx.x >> 2;
    const int h = blockIdx.x & 3;
    const int t = threadIdx.x;
    const int lane = t & 63;
    const int w = t >> 6;
    const int col = lane & 31;
    const int hi = lane >> 5;
    const int jt0 = w * 64;

    // Q fragments from granule planes [h][g][NPOS][16B]
    frag_u qf[2][2];
    const char* qplane = (const char*)Qb + ((size_t)(h * 4) * NPOS + (size_t)i * N) * 16;
    #pragma unroll
    for (int jt = 0; jt < 2; ++jt) {
        int jrow = jt0 + jt * 32 + col;
        #pragma unroll
        for (int cf = 0; cf < 2; ++cf) {
            int g = cf * 2 + hi;
            qf[jt][cf].i = *(const int4*)(qplane + ((size_t)g * NPOS + jrow) * 16);
        }
    }

    // stage K rows from granule planes (coalesced per plane; swizzled LDS slots)
    const char* kplane = (const char*)Kb + ((size_t)(h * 4) * NPOS + (size_t)i * N) * 16;
    #pragma unroll
    for (int it = 0; it < 4; ++it) {
        int4 val = *(const int4*)(kplane + ((size_t)it * NPOS + t) * 16);
        *(int4*)(Klds + t * 64 + ((it ^ ((t >> 1) & 3)) << 4)) = val;
    }
    // stage V^T planes (swizzled)
    const char* vbsrc = (const char*)Vta + ((size_t)h * 32 * NPOS + (size_t)i * N) * 2;
    #pragma unroll
    for (int it = 0; it < 4; ++it) {
        int tt = t + it * 320;
        int a = tt / 40, kg = tt % 40;
        int4 val = *(const int4*)(vbsrc + (size_t)a * NPOS * 2 + kg * 16);
        *(int4*)(Vlds + a * 640 + ((kg ^ (a & 7)) << 4)) = val;
    }
    // mask arrays in MFMA accumulator-row order, pre-scaled by log2(e)
    {
        const float L2E = 1.4426950408889634f;
        int kt_ = t >> 5, hi_ = (t >> 4) & 1, r_ = t & 15;
        int k = kt_ * 32 + (r_ & 3) + 8 * (r_ >> 2) + 4 * hi_;
        float m_ = mask[(size_t)i * N + k];
        mparr[t] = m_ * L2E;
        m2arr[t] = fmaf(100.f, m_, -100.f) * L2E;
    }
    __syncthreads();

    f32x16 accO[2];
    #pragma unroll
    for (int r = 0; r < 16; ++r) { accO[0][r] = 0.f; accO[1][r] = 0.f; }
    float lsum[2] = { 0.f, 0.f };

    // bias row pointers (BpT[h][j][k]) with the lane's 4*hi k-offset folded in
    const float* br0 = BpT + (size_t)h * NPOS + (size_t)(jt0 + col) * N + 4 * hi;
    const float* br1 = br0 + (size_t)32 * N;

    float4 b0[4], b1[4];
    #pragma unroll
    for (int q = 0; q < 4; ++q) b0[q] = *(const float4*)(br0 + 8 * q);  // kt=0, jt=0

#define PROCESS_JT(JT, BB)                                                      \
    {                                                                           \
        f32x16 S;                                                               \
        _Pragma("unroll") for (int r = 0; r < 16; ++r) S[r] = 0.f;              \
        __builtin_amdgcn_s_setprio(1);                                          \
        S = MFMA32(kf0.v, qf[JT][0].v, S);                                      \
        S = MFMA32(kf1.v, qf[JT][1].v, S);                                      \
        __builtin_amdgcn_s_setprio(0);                                          \
        float pe[16];                                                           \
        float l0 = 0.f, l1 = 0.f, l2 = 0.f, l3 = 0.f;                           \
        _Pragma("unroll") for (int q = 0; q < 4; ++q) {                         \
            float sv0 = fmaf(S[4*q+0] + BB[q].x, mk4[q].x, m2v[q].x);           \
            float sv1 = fmaf(S[4*q+1] + BB[q].y, mk4[q].y, m2v[q].y);           \
            float sv2 = fmaf(S[4*q+2] + BB[q].z, mk4[q].z, m2v[q].z);           \
            float sv3 = fmaf(S[4*q+3] + BB[q].w, mk4[q].w, m2v[q].w);           \
            pe[4*q+0] = __ocml_native_exp2_f32(sv0);                            \
            pe[4*q+1] = __ocml_native_exp2_f32(sv1);                            \
            pe[4*q+2] = __ocml_native_exp2_f32(sv2);                            \
            pe[4*q+3] = __ocml_native_exp2_f32(sv3);                            \
            l0 += pe[4*q+0]; l1 += pe[4*q+1];                                   \
            l2 += pe[4*q+2]; l3 += pe[4*q+3];                                   \
        }                                                                       \
        lsum[JT] += (l0 + l1) + (l2 + l3);                                      \
        unsigned p[8];                                                          \
        _Pragma("unroll") for (int q = 0; q < 8; ++q)                           \
            p[q] = pk_bf16(pe[2 * q], pe[2 * q + 1]);                           \
        unsigned x0 = p[0], y0 = p[2];                                          \
        unsigned x1 = p[1], y1 = p[3];                                          \
        unsigned x2 = p[4], y2 = p[6];                                          \
        unsigned x3 = p[5], y3 = p[7];                                          \
        asm("v_permlane32_swap_b32 %0, %1" : "+v"(x0), "+v"(y0));               \
        asm("v_permlane32_swap_b32 %0, %1" : "+v"(x1), "+v"(y1));               \
        asm("v_permlane32_swap_b32 %0, %1" : "+v"(x2), "+v"(y2));               \
        asm("v_permlane32_swap_b32 %0, %1" : "+v"(x3), "+v"(y3));               \
        frag_u bf0, bf1;                                                        \
        bf0.u[0] = x0; bf0.u[1] = x1; bf0.u[2] = y0; bf0.u[3] = y1;             \
        bf1.u[0] = x2; bf1.u[1] = x3; bf1.u[2] = y2; bf1.u[3] = y3;             \
        __builtin_amdgcn_s_setprio(1);                                          \
        accO[JT] = MFMA32(vf0.v, bf0.v, accO[JT]);                              \
        accO[JT] = MFMA32(vf1.v, bf1.v, accO[JT]);                              \
        __builtin_amdgcn_s_setprio(0);                                          \
    }

    for (int kt = 0; kt < 10; ++kt) {
        const int kbase = kt * 32;
        const int krow = kbase + col;
        frag_u kf0, kf1, vf0, vf1;
        kf0.i = *(const int4*)(Klds + krow * 64 + (((0 + hi) ^ ((krow >> 1) & 3)) << 4));
        kf1.i = *(const int4*)(Klds + krow * 64 + (((2 + hi) ^ ((krow >> 1) & 3)) << 4));
        vf0.i = *(const int4*)(Vlds + col * 640 + (((kt * 4 + 0 + hi) ^ (col & 7)) << 4));
        vf1.i = *(const int4*)(Vlds + col * 640 + (((kt * 4 + 2 + hi) ^ (col & 7)) << 4));

        // broadcast mask vectors for this kt (uniform address per half-wave)
        float4 mk4[4], m2v[4];
        const float* mp  = mparr + kbase + hi * 16;
        const float* m2p = m2arr + kbase + hi * 16;
        #pragma unroll
        for (int q = 0; q < 4; ++q) {
            mk4[q] = *(const float4*)(mp + 4 * q);
            m2v[q] = *(const float4*)(m2p + 4 * q);
        }

        // bias for jt=1 of this kt (latency hidden under jt=0 compute)
        #pragma unroll
        for (int q = 0; q < 4; ++q) b1[q] = *(const float4*)(br1 + kbase + 8 * q);

        PROCESS_JT(0, b0)

        // bias for jt=0 of next kt (latency hidden under jt=1 compute)
        if (kt < 9) {
            #pragma unroll
            for (int q = 0; q < 4; ++q) b0[q] = *(const float4*)(br0 + kbase + 32 + 8 * q);
        }

        PROCESS_JT(1, b1)
    }
#undef PROCESS_JT

    // ---- epilogue: normalize, transpose via LDS, gate (granule-plane loads), store bf16 ----
    __syncthreads();   // all waves done reading Klds/Vlds
    float* st = (float*)(smem + w * 8192);   // 32 cols x 33 f32 per wave
    const char* gplane = (const char*)Gb + ((size_t)(h * 4) * NPOS + (size_t)i * N) * 16;

    #pragma unroll
    for (int jt = 0; jt < 2; ++jt) {
        float lt = lsum[jt] + __shfl_xor(lsum[jt], 32);
        float inv = 1.0f / lt;
        #pragma unroll
        for (int r = 0; r < 16; ++r) {
            const int a = (r & 3) + 8 * (r >> 2) + 4 * hi;
            st[col * 33 + a] = accO[jt][r] * inv;
        }
        WAVE_LDS_FENCE();
        {
            int jj = lane & 31;
            int ah0 = hi * 16;
            int jrow = jt0 + jt * 32 + jj;
            int4 g0 = *(const int4*)(gplane + ((size_t)(2 * hi + 0) * NPOS + jrow) * 16);
            int4 g1 = *(const int4*)(gplane + ((size_t)(2 * hi + 1) * NPOS + jrow) * 16);
            unsigned gw[8] = { (unsigned)g0.x, (unsigned)g0.y, (unsigned)g0.z, (unsigned)g0.w,
                               (unsigned)g1.x, (unsigned)g1.y, (unsigned)g1.z, (unsigned)g1.w };
            unsigned pk8[8];
            #pragma unroll
            for (int e = 0; e < 8; ++e) {
                float ge0 = bf16_to_f32((unsigned short)(gw[e] & 0xffffu));
                float ge1 = bf16_to_f32((unsigned short)(gw[e] >> 16));
                pk8[e] = pk_bf16(st[jj * 33 + ah0 + 2 * e + 0] * ge0,
                                 st[jj * 33 + ah0 + 2 * e + 1] * ge1);
            }
            char* dst = (char*)Ob + (((size_t)i * N + jrow) * 128 + h * 32 + ah0) * 2;
            *(int4*)dst = make_int4(pk8[0], pk8[1], pk8[2], pk8[3]);
            *(int4*)(dst + 16) = make_int4(pk8[4], pk8[5], pk8[6], pk8[7]);
        }
        WAVE_LDS_FENCE();
    }
}

// ---------------- Kernel C: MFMA output projection ----------------
// Two-pass epilogue stage: LDS 33280 B => 4 blocks/CU.
__global__ __launch_bounds__(256)
void outproj_kernel(const unsigned short* __restrict__ Ob,
                    const unsigned short* __restrict__ WoF,
                    const float* __restrict__ bo,
                    const float* __restrict__ mask,
                    float* __restrict__ out) {
    __shared__ __align__(16) unsigned char obs[64 * 256];   // bf16 [64][128], swizzled
    __shared__ float stage[4][32 * 33];                     // per-wave, reused acc0 then acc1

    const int t = threadIdx.x;
    const int gpos0 = blockIdx.x * 64;

    {
        const int r = t >> 2, s = t & 3;
        const char* src = (const char*)Ob + ((size_t)(gpos0 + r) * 128 + s * 32) * 2;
        #pragma unroll
        for (int u = 0; u < 4; ++u) {
            int4 v = *(const int4*)(src + u * 16);
            int g = s * 4 + u;
            *(int4*)(obs + r * 256 + ((g ^ (r & 7)) << 4)) = v;
        }
    }
    __syncthreads();

    const int lane = t & 63;
    const int w = t >> 6;
    const int col = lane & 31;
    const int hi = lane >> 5;

    f32x16 acc0, acc1;
    float bocol = bo[w * 32 + col];
    #pragma unroll
    for (int r = 0; r < 16; ++r) { acc0[r] = bocol; acc1[r] = bocol; }

    const char* wf = (const char*)WoF + (size_t)w * 8 * 1024;
    #pragma unroll
    for (int kk = 0; kk < 8; ++kk) {
        frag_u bf, a0, a1;
        bf.i = *(const int4*)(wf + kk * 1024 + lane * 16);
        int row0 = col, row1 = 32 + col;
        a0.i = *(const int4*)(obs + row0 * 256 + (((kk * 2 + hi) ^ (row0 & 7)) << 4));
        a1.i = *(const int4*)(obs + row1 * 256 + (((kk * 2 + hi) ^ (row1 & 7)) << 4));
        acc0 = MFMA32(a0.v, bf.v, acc0);
        acc1 = MFMA32(a1.v, bf.v, acc1);
    }

    float* st = stage[w];
    #pragma unroll
    for (int p = 0; p < 2; ++p) {
        const f32x16& ac = p ? acc1 : acc0;
        #pragma unroll
        for (int r = 0; r < 16; ++r) {
            int patr = (r & 3) + 8 * (r >> 2) + 4 * hi;
            st[col * 33 + patr] = ac[r];
        }
        WAVE_LDS_FENCE();
        {
            int pr = lane & 31;                 // position within this 32-row group
            int row = p * 32 + pr;              // tile row
            int c0 = (lane >> 5) * 16;          // half-wave covers 16 of the 32 cols
            float mv = mask[gpos0 + row];
            float4* dst = (float4*)(out + (size_t)(gpos0 + row) * 128 + w * 32 + c0);
            #pragma unroll
            for (int u = 0; u < 4; ++u) {
                float4 o;
                o.x = st[(c0 + 4 * u + 0) * 33 + pr] * mv;
                o.y = st[(c0 + 4 * u + 1) * 33 + pr] * mv;
                o.z = st[(c0 + 4 * u + 2) * 33 + pr] * mv;
                o.w = st[(c0 + 4 * u + 3) * 33 + pr] * mv;
                dst[u] = o;
            }
        }
        WAVE_LDS_FENCE();
    }
}

// ---------------- launch ----------------
extern "C" void kernel_launch(void* const* d_in, const int* in_sizes, int n_in,
                              void* d_out, int out_size, void* d_ws, size_t ws_size,
                              hipStream_t stream) {
    const float* x2d    = (const float*)d_in[0];
    const float* mask   = (const float*)d_in[1];
    const float* norm_w = (const float*)d_in[2];
    const float* norm_b = (const float*)d_in[3];
    const float* Wq     = (const float*)d_in[4];
    const float* Wk     = (const float*)d_in[5];
    const float* Wv     = (const float*)d_in[6];
    const float* Wb     = (const float*)d_in[7];
    const float* Wg     = (const float*)d_in[8];
    const float* bg     = (const float*)d_in[9];
    const float* Wo     = (const float*)d_in[10];
    const float* bo     = (const float*)d_in[11];
    float* out = (float*)d_out;

    // workspace carve (bytes): Bp,BpT f32[H*NPOS]; bf16: Qb,Kb,Vta,Gb,Ob [NPOS*C]; WF bf16[5*16384]
    char* ws = (char*)d_ws;
    float* Bp  = (float*)ws;                                   ws += (size_t)H * NPOS * 4;
    float* BpT = (float*)ws;                                   ws += (size_t)H * NPOS * 4;
    unsigned short* Qb  = (unsigned short*)ws;                 ws += (size_t)NPOS * C * 2;
    unsigned short* Kb  = (unsigned short*)ws;                 ws += (size_t)NPOS * C * 2;
    unsigned short* Vta = (unsigned short*)ws;                 ws += (size_t)NPOS * C * 2;
    unsigned short* Gb  = (unsigned short*)ws;                 ws += (size_t)NPOS * C * 2;
    unsigned short* Ob  = (unsigned short*)ws;                 ws += (size_t)NPOS * C * 2;
    unsigned short* WF  = (unsigned short*)ws;                 // 5 * 32768 B
    unsigned short* WoF = WF + (size_t)4 * 16384;

    wprep_kernel<<<40, 256, 0, stream>>>(Wq, Wk, Wv, Wg, Wo, WF);

    ln_proj_kernel<<<NPOS / 32, 256, 0, stream>>>(x2d, norm_w, norm_b, Wb, bg,
                                                  WF, Qb, Kb, Vta, Gb, Bp);

    btrans_kernel<<<H * 25, 256, 0, stream>>>(Bp, BpT);

    attn_kernel<<<N * H, 320, 0, stream>>>(Qb, Kb, Vta, Gb, BpT, mask, Ob);

    outproj_kernel<<<NPOS / 64, 256, 0, stream>>>(Ob, WoF, bo, mask, out);
}

// Round 20
// 179.591 us; speedup vs baseline: 1.0418x; 1.0418x over previous
//
#include <hip/hip_runtime.h>
#include <hip/hip_bf16.h>
#include <math.h>

#define N 320
#define C 128
#define A 32
#define H 4
#define NPOS (N*N)

typedef __attribute__((ext_vector_type(8))) __bf16 bf16x8;
typedef __attribute__((ext_vector_type(16))) float f32x16;

union frag_u { int4 i; bf16x8 v; unsigned u[4]; };

#define MFMA32(va, vb, vc) __builtin_amdgcn_mfma_f32_32x32x16_bf16((va), (vb), (vc), 0, 0, 0)

extern "C" __device__ float __ocml_native_exp2_f32(float);

// wave-local LDS fence: order ds_write -> ds_read within a wave without
// draining vmcnt (global stores stay in flight).
#define WAVE_LDS_FENCE() do { \
    asm volatile("s_waitcnt lgkmcnt(0)" ::: "memory"); \
    __builtin_amdgcn_sched_barrier(0); \
} while (0)

static __device__ __forceinline__ unsigned pk_bf16(float lo, float hi) {
    union { __hip_bfloat162 h; unsigned u; } cv;
    cv.h = __float22bfloat162_rn(make_float2(lo, hi));
    return cv.u;
}

static __device__ __forceinline__ float bf16_to_f32(unsigned short u) {
    union { unsigned u; float f; } c;
    c.u = ((unsigned)u) << 16;
    return c.f;
}

// ---------------- Kernel W: weights -> bf16 B-fragment order ----------------
__global__ __launch_bounds__(256)
void wprep_kernel(const float* __restrict__ Wq,
                  const float* __restrict__ Wk,
                  const float* __restrict__ Wv,
                  const float* __restrict__ Wg,
                  const float* __restrict__ Wo,
                  unsigned short* __restrict__ WF) {
    const float isq = 0.17677669529663687f; // 1/sqrt(32)
    int tid = blockIdx.x * 256 + threadIdx.x;   // 10240 total
    int lane = tid & 63;
    int kk = (tid >> 6) & 7;
    int ct = (tid >> 9) & 3;
    int mat = tid >> 11;                        // 0..4
    const float* src = (mat == 0) ? Wq : (mat == 1) ? Wk : (mat == 2) ? Wv
                     : (mat == 3) ? Wg : Wo;
    float scl = (mat == 0) ? isq : 1.0f;
    int col = ct * 32 + (lane & 31);
    int c0 = kk * 16 + (lane >> 5) * 8;
    float v[8];
    #pragma unroll
    for (int e = 0; e < 8; e++) {
        int rr = c0 + e;
        int srow = (mat == 4) ? (((rr & 31) << 2) | (rr >> 5)) : rr;
        v[e] = src[(size_t)srow * 128 + col] * scl;
    }
    int4 out;
    out.x = pk_bf16(v[0], v[1]);
    out.y = pk_bf16(v[2], v[3]);
    out.z = pk_bf16(v[4], v[5]);
    out.w = pk_bf16(v[6], v[7]);
    *(int4*)((char*)WF + (size_t)tid * 16) = out;
}

// ---------------- Kernel T: bias transpose Bp[h][k*N+j] -> BpT[h][j*N+k] ----------------
__global__ __launch_bounds__(256)
void btrans_kernel(const float* __restrict__ Bp, float* __restrict__ BpT) {
    __shared__ float tile[64][65];
    const int b = blockIdx.x;
    const int h = b / 25;
    const int bk = (b % 25) / 5;
    const int bj = b % 5;
    const int k0 = bk * 64, j0 = bj * 64;
    const float* src = Bp + (size_t)h * NPOS;
    float* dst = BpT + (size_t)h * NPOS;
    const int t = threadIdx.x;
    #pragma unroll
    for (int u = 0; u < 16; ++u) {
        int idx = u * 256 + t;
        int kk = idx >> 6, jj = idx & 63;
        tile[kk][jj] = src[(size_t)(k0 + kk) * N + j0 + jj];
    }
    __syncthreads();
    #pragma unroll
    for (int u = 0; u < 16; ++u) {
        int idx = u * 256 + t;
        int jj = idx >> 6, kk = idx & 63;
        dst[(size_t)(j0 + jj) * N + k0 + kk] = tile[kk][jj];
    }
}

// ---------------- Kernel A: LayerNorm + MFMA projections ---------------- (round-18 proven version)
// 3200 blocks x 256 threads; 32 positions per block; wave w computes matrix w.
// LDS = 16896 B -> 8 blocks/CU (wave-cap). Stage-transpose epilogue (all waves).
__global__ __launch_bounds__(256)
void ln_proj_kernel(const float* __restrict__ x2d,
                    const float* __restrict__ norm_w,
                    const float* __restrict__ norm_b,
                    const float* __restrict__ Wb,
                    const float* __restrict__ bg,
                    const unsigned short* __restrict__ WF,
                    unsigned short* __restrict__ Qb,
                    unsigned short* __restrict__ Kb,
                    unsigned short* __restrict__ Vta,
                    unsigned short* __restrict__ Gb,
                    float* __restrict__ Bp) {
    // overlay: xnb (8192 B, dead after A-frag load) aliases stage (16896 B)
    __shared__ __align__(16) unsigned char shbuf[16896];
    unsigned char* xnb = shbuf;                 // bf16 [32][128], swizzled granules

    const int t = threadIdx.x;
    const int gpos0 = blockIdx.x * 32;

    // ---- Phase 1: LN + bias projection + bf16 pack to LDS ----
    // 8 lanes per position; lane s covers channels [s*16, s*16+16)
    {
        const int r = t >> 3, s = t & 7;
        const float4* src = (const float4*)(x2d + (size_t)(gpos0 + r) * 128 + s * 16);
        float4 xv[4];
        #pragma unroll
        for (int u = 0; u < 4; u++) xv[u] = src[u];
        float sum = 0.f, sq = 0.f;
        #pragma unroll
        for (int u = 0; u < 4; u++) {
            sum += xv[u].x + xv[u].y + xv[u].z + xv[u].w;
            sq += xv[u].x * xv[u].x + xv[u].y * xv[u].y
                + xv[u].z * xv[u].z + xv[u].w * xv[u].w;
        }
        sum += __shfl_xor(sum, 1); sum += __shfl_xor(sum, 2); sum += __shfl_xor(sum, 4);
        sq  += __shfl_xor(sq, 1);  sq  += __shfl_xor(sq, 2);  sq  += __shfl_xor(sq, 4);
        float mean = sum * (1.0f / 128.0f);
        float var  = sq * (1.0f / 128.0f) - mean * mean;
        float rstd = rsqrtf(var + 1e-5f);

        const float4* wsrc = (const float4*)(norm_w + s * 16);
        const float4* bsrc = (const float4*)(norm_b + s * 16);
        const float4* wb4  = (const float4*)Wb;
        float pb0 = 0.f, pb1 = 0.f, pb2 = 0.f, pb3 = 0.f;
        float4 xe;
        #pragma unroll
        for (int u = 0; u < 4; u++) {
            float4 wv = wsrc[u], bv = bsrc[u], x4 = xv[u];
            float4 xn;
            xn.x = (x4.x - mean) * rstd * wv.x + bv.x;
            xn.y = (x4.y - mean) * rstd * wv.y + bv.y;
            xn.z = (x4.z - mean) * rstd * wv.z + bv.z;
            xn.w = (x4.w - mean) * rstd * wv.w + bv.w;
            int cb = s * 16 + u * 4;
            float4 w0 = wb4[cb + 0], w1 = wb4[cb + 1], w2 = wb4[cb + 2], w3 = wb4[cb + 3];
            pb0 = fmaf(xn.x, w0.x, fmaf(xn.y, w1.x, fmaf(xn.z, w2.x, fmaf(xn.w, w3.x, pb0))));
            pb1 = fmaf(xn.x, w0.y, fmaf(xn.y, w1.y, fmaf(xn.z, w2.y, fmaf(xn.w, w3.y, pb1))));
            pb2 = fmaf(xn.x, w0.z, fmaf(xn.y, w1.z, fmaf(xn.z, w2.z, fmaf(xn.w, w3.z, pb2))));
            pb3 = fmaf(xn.x, w0.w, fmaf(xn.y, w1.w, fmaf(xn.z, w2.w, fmaf(xn.w, w3.w, pb3))));
            if (u & 1) {
                int g = s * 2 + (u >> 1);
                int4 gr;
                gr.x = pk_bf16(xe.x, xe.y);
                gr.y = pk_bf16(xe.z, xe.w);
                gr.z = pk_bf16(xn.x, xn.y);
                gr.w = pk_bf16(xn.z, xn.w);
                *(int4*)(xnb + r * 256 + ((g ^ (r & 7)) << 4)) = gr;
            } else {
                xe = xn;
            }
        }
        pb0 += __shfl_xor(pb0, 1); pb0 += __shfl_xor(pb0, 2); pb0 += __shfl_xor(pb0, 4);
        pb1 += __shfl_xor(pb1, 1); pb1 += __shfl_xor(pb1, 2); pb1 += __shfl_xor(pb1, 4);
        pb2 += __shfl_xor(pb2, 1); pb2 += __shfl_xor(pb2, 2); pb2 += __shfl_xor(pb2, 4);
        pb3 += __shfl_xor(pb3, 1); pb3 += __shfl_xor(pb3, 2); pb3 += __shfl_xor(pb3, 4);
        if (s < 4) {
            float pbsel = (s == 0) ? pb0 : (s == 1) ? pb1 : (s == 2) ? pb2 : pb3;
            Bp[(size_t)s * NPOS + gpos0 + r] = pbsel;
        }
    }
    __syncthreads();

    // ---- Phase 2: per-wave MFMA GEMM + stage-transpose epilogue ----
    const int lane = t & 63;
    const int w = t >> 6;
    const int col = lane & 31;
    const int hi = lane >> 5;

    frag_u af[8];
    #pragma unroll
    for (int kk = 0; kk < 8; kk++)
        af[kk].i = *(const int4*)(xnb + col * 256 + (((kk * 2 + hi) ^ (col & 7)) << 4));
    __syncthreads();   // xnb dead; stage may now alias it

    const char* wf = (const char*)WF + (size_t)w * 4 * 8 * 1024;
    float* stage_w = (float*)shbuf + w * 1056;   // 32*33 floats per wave

    for (int ct = 0; ct < 4; ct++) {
        f32x16 acc;
        #pragma unroll
        for (int r = 0; r < 16; r++) acc[r] = 0.f;
        #pragma unroll
        for (int kk = 0; kk < 8; kk++) {
            frag_u bf;
            bf.i = *(const int4*)(wf + (ct * 8 + kk) * 1024 + lane * 16);
            acc = MFMA32(af[kk].v, bf.v, acc);
        }
        // stage: [out-ch col][pos patr], stride 33
        #pragma unroll
        for (int r = 0; r < 16; r++) {
            int patr = (r & 3) + 8 * (r >> 2) + 4 * hi;
            stage_w[col * 33 + patr] = acc[r];
        }
        WAVE_LDS_FENCE();   // lgkmcnt only: stage visible wave-wide, stores stay in flight
        if (w < 2) {
            // Q / K granule planes [h*4+ct][pos][16B]; hi-half writes 8B
            char* dst = (w == 0) ? (char*)Qb : (char*)Kb;
            #pragma unroll
            for (int h = 0; h < 4; h++) {
                float f[4];
                #pragma unroll
                for (int e = 0; e < 4; e++)
                    f[e] = stage_w[((hi * 4 + e) * 4 + h) * 33 + col];
                uint2 val;
                val.x = pk_bf16(f[0], f[1]);
                val.y = pk_bf16(f[2], f[3]);
                *(uint2*)(dst + ((size_t)(h * 4 + ct) * NPOS + gpos0 + col) * 16 + hi * 8) = val;
            }
        } else if (w == 2) {
            // V planes [h*32+a][pos]; half handles 16 positions (32B contiguous per plane)
            int cc = col, half = hi;
            int plane = (cc & 3) * 32 + ct * 8 + (cc >> 2);
            unsigned pk[8];
            #pragma unroll
            for (int j2 = 0; j2 < 8; j2++)
                pk[j2] = pk_bf16(stage_w[cc * 33 + half * 16 + 2 * j2],
                                 stage_w[cc * 33 + half * 16 + 2 * j2 + 1]);
            int4* dst = (int4*)((char*)Vta + ((size_t)plane * NPOS + gpos0 + half * 16) * 2);
            dst[0] = make_int4(pk[0], pk[1], pk[2], pk[3]);
            dst[1] = make_int4(pk[4], pk[5], pk[6], pk[7]);
        } else {
            // G granule planes [h*4+ct][pos][16B], sigmoid(acc + bg); hi-half 8B
            #pragma unroll
            for (int h = 0; h < 4; h++) {
                float f[4];
                #pragma unroll
                for (int e = 0; e < 4; e++) {
                    float z = stage_w[((hi * 4 + e) * 4 + h) * 33 + col]
                            + bg[ct * 32 + (hi * 4 + e) * 4 + h];
                    f[e] = 1.0f / (1.0f + __expf(-z));
                }
                uint2 val;
                val.x = pk_bf16(f[0], f[1]);
                val.y = pk_bf16(f[2], f[3]);
                *(uint2*)((char*)Gb + ((size_t)(h * 4 + ct) * NPOS + gpos0 + col) * 16 + hi * 8) = val;
            }
        }
        WAVE_LDS_FENCE();   // reads done before next ct overwrites stage
    }
}

// ---------------- Kernel B: MFMA attention per (i,h) ----------------
// round-15 structure + exp2 fold: log2e folded into the mask arrays, exp
// computed with native exp2 (deletes 32 v_mul per kt from the sv->exp chain).
__global__ __launch_bounds__(320, 2)
void attn_kernel(const unsigned short* __restrict__ Qb,
                 const unsigned short* __restrict__ Kb,
                 const unsigned short* __restrict__ Vta,
                 const unsigned short* __restrict__ Gb,
                 const float* __restrict__ BpT,
                 const float* __restrict__ mask,
                 unsigned short* __restrict__ Ob) {
    __shared__ __align__(16) unsigned char smem[40960];   // K[20480] | V[20480]; reused as epilogue stage
    __shared__ float mparr[320];   // mask*log2e, MFMA-row order
    __shared__ float m2arr[320];   // (100*mask-100)*log2e, MFMA-row order
    unsigned char* Klds = smem;
    unsigned char* Vlds = smem + 20480;

    const int i = blockIdx.x >> 2;
    const int h = blockIdx.x & 3;
    const int t = threadIdx.x;
    const int lane = t & 63;
    const int w = t >> 6;
    const int col = lane & 31;
    const int hi = lane >> 5;
    const int jt0 = w * 64;

    // Q fragments from granule planes [h][g][NPOS][16B]
    frag_u qf[2][2];
    const char* qplane = (const char*)Qb + ((size_t)(h * 4) * NPOS + (size_t)i * N) * 16;
    #pragma unroll
    for (int jt = 0; jt < 2; ++jt) {
        int jrow = jt0 + jt * 32 + col;
        #pragma unroll
        for (int cf = 0; cf < 2; ++cf) {
            int g = cf * 2 + hi;
            qf[jt][cf].i = *(const int4*)(qplane + ((size_t)g * NPOS + jrow) * 16);
        }
    }

    // stage K rows from granule planes (coalesced per plane; swizzled LDS slots)
    const char* kplane = (const char*)Kb + ((size_t)(h * 4) * NPOS + (size_t)i * N) * 16;
    #pragma unroll
    for (int it = 0; it < 4; ++it) {
        int4 val = *(const int4*)(kplane + ((size_t)it * NPOS + t) * 16);
        *(int4*)(Klds + t * 64 + ((it ^ ((t >> 1) & 3)) << 4)) = val;
    }
    // stage V^T planes (swizzled)
    const char* vbsrc = (const char*)Vta + ((size_t)h * 32 * NPOS + (size_t)i * N) * 2;
    #pragma unroll
    for (int it = 0; it < 4; ++it) {
        int tt = t + it * 320;
        int a = tt / 40, kg = tt % 40;
        int4 val = *(const int4*)(vbsrc + (size_t)a * NPOS * 2 + kg * 16);
        *(int4*)(Vlds + a * 640 + ((kg ^ (a & 7)) << 4)) = val;
    }
    // mask arrays in MFMA accumulator-row order, pre-scaled by log2(e)
    {
        const float L2E = 1.4426950408889634f;
        int kt_ = t >> 5, hi_ = (t >> 4) & 1, r_ = t & 15;
        int k = kt_ * 32 + (r_ & 3) + 8 * (r_ >> 2) + 4 * hi_;
        float m_ = mask[(size_t)i * N + k];
        mparr[t] = m_ * L2E;
        m2arr[t] = fmaf(100.f, m_, -100.f) * L2E;
    }
    __syncthreads();

    f32x16 accO[2];
    #pragma unroll
    for (int r = 0; r < 16; ++r) { accO[0][r] = 0.f; accO[1][r] = 0.f; }
    float lsum[2] = { 0.f, 0.f };

    // bias row pointers (BpT[h][j][k]) with the lane's 4*hi k-offset folded in
    const float* br0 = BpT + (size_t)h * NPOS + (size_t)(jt0 + col) * N + 4 * hi;
    const float* br1 = br0 + (size_t)32 * N;

    float4 b0[4], b1[4];
    #pragma unroll
    for (int q = 0; q < 4; ++q) b0[q] = *(const float4*)(br0 + 8 * q);  // kt=0, jt=0

#define PROCESS_JT(JT, BB)                                                      \
    {                                                                           \
        f32x16 S;                                                               \
        _Pragma("unroll") for (int r = 0; r < 16; ++r) S[r] = 0.f;              \
        __builtin_amdgcn_s_setprio(1);                                          \
        S = MFMA32(kf0.v, qf[JT][0].v, S);                                      \
        S = MFMA32(kf1.v, qf[JT][1].v, S);                                      \
        __builtin_amdgcn_s_setprio(0);                                          \
        float pe[16];                                                           \
        float l0 = 0.f, l1 = 0.f, l2 = 0.f, l3 = 0.f;                           \
        _Pragma("unroll") for (int q = 0; q < 4; ++q) {                         \
            float sv0 = fmaf(S[4*q+0] + BB[q].x, mk4[q].x, m2v[q].x);           \
            float sv1 = fmaf(S[4*q+1] + BB[q].y, mk4[q].y, m2v[q].y);           \
            float sv2 = fmaf(S[4*q+2] + BB[q].z, mk4[q].z, m2v[q].z);           \
            float sv3 = fmaf(S[4*q+3] + BB[q].w, mk4[q].w, m2v[q].w);           \
            pe[4*q+0] = __ocml_native_exp2_f32(sv0);                            \
            pe[4*q+1] = __ocml_native_exp2_f32(sv1);                            \
            pe[4*q+2] = __ocml_native_exp2_f32(sv2);                            \
            pe[4*q+3] = __ocml_native_exp2_f32(sv3);                            \
            l0 += pe[4*q+0]; l1 += pe[4*q+1];                                   \
            l2 += pe[4*q+2]; l3 += pe[4*q+3];                                   \
        }                                                                       \
        lsum[JT] += (l0 + l1) + (l2 + l3);                                      \
        unsigned p[8];                                                          \
        _Pragma("unroll") for (int q = 0; q < 8; ++q)                           \
            p[q] = pk_bf16(pe[2 * q], pe[2 * q + 1]);                           \
        unsigned x0 = p[0], y0 = p[2];                                          \
        unsigned x1 = p[1], y1 = p[3];                                          \
        unsigned x2 = p[4], y2 = p[6];                                          \
        unsigned x3 = p[5], y3 = p[7];                                          \
        asm("v_permlane32_swap_b32 %0, %1" : "+v"(x0), "+v"(y0));               \
        asm("v_permlane32_swap_b32 %0, %1" : "+v"(x1), "+v"(y1));               \
        asm("v_permlane32_swap_b32 %0, %1" : "+v"(x2), "+v"(y2));               \
        asm("v_permlane32_swap_b32 %0, %1" : "+v"(x3), "+v"(y3));               \
        frag_u bf0, bf1;                                                        \
        bf0.u[0] = x0; bf0.u[1] = x1; bf0.u[2] = y0; bf0.u[3] = y1;             \
        bf1.u[0] = x2; bf1.u[1] = x3; bf1.u[2] = y2; bf1.u[3] = y3;             \
        __builtin_amdgcn_s_setprio(1);                                          \
        accO[JT] = MFMA32(vf0.v, bf0.v, accO[JT]);                              \
        accO[JT] = MFMA32(vf1.v, bf1.v, accO[JT]);                              \
        __builtin_amdgcn_s_setprio(0);                                          \
    }

    for (int kt = 0; kt < 10; ++kt) {
        const int kbase = kt * 32;
        const int krow = kbase + col;
        frag_u kf0, kf1, vf0, vf1;
        kf0.i = *(const int4*)(Klds + krow * 64 + (((0 + hi) ^ ((krow >> 1) & 3)) << 4));
        kf1.i = *(const int4*)(Klds + krow * 64 + (((2 + hi) ^ ((krow >> 1) & 3)) << 4));
        vf0.i = *(const int4*)(Vlds + col * 640 + (((kt * 4 + 0 + hi) ^ (col & 7)) << 4));
        vf1.i = *(const int4*)(Vlds + col * 640 + (((kt * 4 + 2 + hi) ^ (col & 7)) << 4));

        // broadcast mask vectors for this kt (uniform address per half-wave)
        float4 mk4[4], m2v[4];
        const float* mp  = mparr + kbase + hi * 16;
        const float* m2p = m2arr + kbase + hi * 16;
        #pragma unroll
        for (int q = 0; q < 4; ++q) {
            mk4[q] = *(const float4*)(mp + 4 * q);
            m2v[q] = *(const float4*)(m2p + 4 * q);
        }

        // bias for jt=1 of this kt (latency hidden under jt=0 compute)
        #pragma unroll
        for (int q = 0; q < 4; ++q) b1[q] = *(const float4*)(br1 + kbase + 8 * q);

        PROCESS_JT(0, b0)

        // bias for jt=0 of next kt (latency hidden under jt=1 compute)
        if (kt < 9) {
            #pragma unroll
            for (int q = 0; q < 4; ++q) b0[q] = *(const float4*)(br0 + kbase + 32 + 8 * q);
        }

        PROCESS_JT(1, b1)
    }
#undef PROCESS_JT

    // ---- epilogue: normalize, transpose via LDS, gate (granule-plane loads), store bf16 ----
    __syncthreads();   // all waves done reading Klds/Vlds
    float* st = (float*)(smem + w * 8192);   // 32 cols x 33 f32 per wave
    const char* gplane = (const char*)Gb + ((size_t)(h * 4) * NPOS + (size_t)i * N) * 16;

    #pragma unroll
    for (int jt = 0; jt < 2; ++jt) {
        float lt = lsum[jt] + __shfl_xor(lsum[jt], 32);
        float inv = 1.0f / lt;
        #pragma unroll
        for (int r = 0; r < 16; ++r) {
            const int a = (r & 3) + 8 * (r >> 2) + 4 * hi;
            st[col * 33 + a] = accO[jt][r] * inv;
        }
        WAVE_LDS_FENCE();
        {
            int jj = lane & 31;
            int ah0 = hi * 16;
            int jrow = jt0 + jt * 32 + jj;
            int4 g0 = *(const int4*)(gplane + ((size_t)(2 * hi + 0) * NPOS + jrow) * 16);
            int4 g1 = *(const int4*)(gplane + ((size_t)(2 * hi + 1) * NPOS + jrow) * 16);
            unsigned gw[8] = { (unsigned)g0.x, (unsigned)g0.y, (unsigned)g0.z, (unsigned)g0.w,
                               (unsigned)g1.x, (unsigned)g1.y, (unsigned)g1.z, (unsigned)g1.w };
            unsigned pk8[8];
            #pragma unroll
            for (int e = 0; e < 8; ++e) {
                float ge0 = bf16_to_f32((unsigned short)(gw[e] & 0xffffu));
                float ge1 = bf16_to_f32((unsigned short)(gw[e] >> 16));
                pk8[e] = pk_bf16(st[jj * 33 + ah0 + 2 * e + 0] * ge0,
                                 st[jj * 33 + ah0 + 2 * e + 1] * ge1);
            }
            char* dst = (char*)Ob + (((size_t)i * N + jrow) * 128 + h * 32 + ah0) * 2;
            *(int4*)dst = make_int4(pk8[0], pk8[1], pk8[2], pk8[3]);
            *(int4*)(dst + 16) = make_int4(pk8[4], pk8[5], pk8[6], pk8[7]);
        }
        WAVE_LDS_FENCE();
    }
}

// ---------------- Kernel C: MFMA output projection ----------------
// Two-pass epilogue stage: LDS 33280 B => 4 blocks/CU.
__global__ __launch_bounds__(256)
void outproj_kernel(const unsigned short* __restrict__ Ob,
                    const unsigned short* __restrict__ WoF,
                    const float* __restrict__ bo,
                    const float* __restrict__ mask,
                    float* __restrict__ out) {
    __shared__ __align__(16) unsigned char obs[64 * 256];   // bf16 [64][128], swizzled
    __shared__ float stage[4][32 * 33];                     // per-wave, reused acc0 then acc1

    const int t = threadIdx.x;
    const int gpos0 = blockIdx.x * 64;

    {
        const int r = t >> 2, s = t & 3;
        const char* src = (const char*)Ob + ((size_t)(gpos0 + r) * 128 + s * 32) * 2;
        #pragma unroll
        for (int u = 0; u < 4; ++u) {
            int4 v = *(const int4*)(src + u * 16);
            int g = s * 4 + u;
            *(int4*)(obs + r * 256 + ((g ^ (r & 7)) << 4)) = v;
        }
    }
    __syncthreads();

    const int lane = t & 63;
    const int w = t >> 6;
    const int col = lane & 31;
    const int hi = lane >> 5;

    f32x16 acc0, acc1;
    float bocol = bo[w * 32 + col];
    #pragma unroll
    for (int r = 0; r < 16; ++r) { acc0[r] = bocol; acc1[r] = bocol; }

    const char* wf = (const char*)WoF + (size_t)w * 8 * 1024;
    #pragma unroll
    for (int kk = 0; kk < 8; ++kk) {
        frag_u bf, a0, a1;
        bf.i = *(const int4*)(wf + kk * 1024 + lane * 16);
        int row0 = col, row1 = 32 + col;
        a0.i = *(const int4*)(obs + row0 * 256 + (((kk * 2 + hi) ^ (row0 & 7)) << 4));
        a1.i = *(const int4*)(obs + row1 * 256 + (((kk * 2 + hi) ^ (row1 & 7)) << 4));
        acc0 = MFMA32(a0.v, bf.v, acc0);
        acc1 = MFMA32(a1.v, bf.v, acc1);
    }

    float* st = stage[w];
    #pragma unroll
    for (int p = 0; p < 2; ++p) {
        const f32x16& ac = p ? acc1 : acc0;
        #pragma unroll
        for (int r = 0; r < 16; ++r) {
            int patr = (r & 3) + 8 * (r >> 2) + 4 * hi;
            st[col * 33 + patr] = ac[r];
        }
        WAVE_LDS_FENCE();
        {
            int pr = lane & 31;                 // position within this 32-row group
            int row = p * 32 + pr;              // tile row
            int c0 = (lane >> 5) * 16;          // half-wave covers 16 of the 32 cols
            float mv = mask[gpos0 + row];
            float4* dst = (float4*)(out + (size_t)(gpos0 + row) * 128 + w * 32 + c0);
            #pragma unroll
            for (int u = 0; u < 4; ++u) {
                float4 o;
                o.x = st[(c0 + 4 * u + 0) * 33 + pr] * mv;
                o.y = st[(c0 + 4 * u + 1) * 33 + pr] * mv;
                o.z = st[(c0 + 4 * u + 2) * 33 + pr] * mv;
                o.w = st[(c0 + 4 * u + 3) * 33 + pr] * mv;
                dst[u] = o;
            }
        }
        WAVE_LDS_FENCE();
    }
}

// ---------------- launch ----------------
extern "C" void kernel_launch(void* const* d_in, const int* in_sizes, int n_in,
                              void* d_out, int out_size, void* d_ws, size_t ws_size,
                              hipStream_t stream) {
    const float* x2d    = (const float*)d_in[0];
    const float* mask   = (const float*)d_in[1];
    const float* norm_w = (const float*)d_in[2];
    const float* norm_b = (const float*)d_in[3];
    const float* Wq     = (const float*)d_in[4];
    const float* Wk     = (const float*)d_in[5];
    const float* Wv     = (const float*)d_in[6];
    const float* Wb     = (const float*)d_in[7];
    const float* Wg     = (const float*)d_in[8];
    const float* bg     = (const float*)d_in[9];
    const float* Wo     = (const float*)d_in[10];
    const float* bo     = (const float*)d_in[11];
    float* out = (float*)d_out;

    // workspace carve (bytes): Bp,BpT f32[H*NPOS]; bf16: Qb,Kb,Vta,Gb,Ob [NPOS*C]; WF bf16[5*16384]
    char* ws = (char*)d_ws;
    float* Bp  = (float*)ws;                                   ws += (size_t)H * NPOS * 4;
    float* BpT = (float*)ws;                                   ws += (size_t)H * NPOS * 4;
    unsigned short* Qb  = (unsigned short*)ws;                 ws += (size_t)NPOS * C * 2;
    unsigned short* Kb  = (unsigned short*)ws;                 ws += (size_t)NPOS * C * 2;
    unsigned short* Vta = (unsigned short*)ws;                 ws += (size_t)NPOS * C * 2;
    unsigned short* Gb  = (unsigned short*)ws;                 ws += (size_t)NPOS * C * 2;
    unsigned short* Ob  = (unsigned short*)ws;                 ws += (size_t)NPOS * C * 2;
    unsigned short* WF  = (unsigned short*)ws;                 // 5 * 32768 B
    unsigned short* WoF = WF + (size_t)4 * 16384;

    wprep_kernel<<<40, 256, 0, stream>>>(Wq, Wk, Wv, Wg, Wo, WF);

    ln_proj_kernel<<<NPOS / 32, 256, 0, stream>>>(x2d, norm_w, norm_b, Wb, bg,
                                                  WF, Qb, Kb, Vta, Gb, Bp);

    btrans_kernel<<<H * 25, 256, 0, stream>>>(Bp, BpT);

    attn_kernel<<<N * H, 320, 0, stream>>>(Qb, Kb, Vta, Gb, BpT, mask, Ob);

    outproj_kernel<<<NPOS / 64, 256, 0, stream>>>(Ob, WoF, bo, mask, out);
}